// Round 9
// baseline (740.127 us; speedup 1.0000x reference)
//
#include <hip/hip_runtime.h>
#include <hip/hip_bf16.h>
#include <hip/hip_fp16.h>

// SimpleRNN: B=64, S=2048, IN=256, H=128, OUT=3 (all fp32)
// Phase 1: xproj MFMA GEMM (byte-identical to r16/r17; stores xp [t][b][h]).
// Phase 2 (r18): 2 ROWS PER LANE. r17's step cost (583 cyc) is dominated by
//   LDS return traffic: every lane reading a 128-B h-slice = 32 KB/step
//   through one CU's LDS pipe (~130-380 cyc at measured 12 cyc/ds_read_b128).
//   Thread (P,q) = row-pair P (rows 2P,2P+1), 32-half slice q: the SAME 64-B
//   slice read feeds BOTH rows' dots -> 16 KB/step, 4 reads/lane instead of 8.
//   Weight regs: 2 rows x 32 halves = 32 half2 = the proven residency budget.
//   Quad (4-lane) DPP reduce per row, one b32 half2 write per pair (same-addr
//   dup writes measured conflict-free in r17), float2 xp prefetch 4-deep.

#define RNN_B   64
#define RNN_S   2048
#define RNN_IN  256
#define RNN_H   128
#define RNN_OUT 3

typedef _Float16 half2v __attribute__((ext_vector_type(2)));
typedef _Float16 half4 __attribute__((ext_vector_type(4)));
typedef _Float16 half8 __attribute__((ext_vector_type(8)));
typedef float f32x4 __attribute__((ext_vector_type(4)));

#if __has_builtin(__builtin_amdgcn_fdot2)
#define FDOT2(a, b, c) __builtin_amdgcn_fdot2((a), (b), (c), false)
#else
#define FDOT2(a, b, c) \
  fmaf((float)(a).x, (float)(b).x, fmaf((float)(a).y, (float)(b).y, (c)))
#endif

// LDS-only barrier: drains lgkm (LDS) but NOT vmcnt, so global prefetch
// loads stay in flight across the barrier.
__device__ __forceinline__ void block_sync_lds() {
  asm volatile("s_waitcnt lgkmcnt(0)" ::: "memory");
  __builtin_amdgcn_s_barrier();
}

// ---------------------------------------------------------------------------
// Phase 1: f16 MFMA GEMM  C[M=131072, N=128] = A[M,256] * B[128,256]^T + bias
// (byte-identical to rounds 5-8 for attribution; epilogue stores xp[t][b][h])
// ---------------------------------------------------------------------------
#define XLOADC(SET, KC)                                                       \
  {                                                                           \
    const int _kc = (KC);                                                     \
    _Pragma("unroll")                                                         \
    for (int p = 0; p < 4; ++p) {                                             \
      const int row = lr + 32 * p;                                            \
      SET##a[p] = *(const float4*)&x[(size_t)(m0 + row) * RNN_IN + _kc + lc]; \
      SET##b[p] = *(const float4*)&Wxh[(size_t)row * RNN_IN + _kc + lc];      \
    }                                                                         \
  }

#define XSTORE(SET)                                                 \
  {                                                                 \
    _Pragma("unroll")                                               \
    for (int p = 0; p < 4; ++p) {                                   \
      const int row = lr + 32 * p;                                  \
      half4 ha, hb;                                                 \
      ha.x = (_Float16)SET##a[p].x; ha.y = (_Float16)SET##a[p].y;   \
      ha.z = (_Float16)SET##a[p].z; ha.w = (_Float16)SET##a[p].w;   \
      hb.x = (_Float16)SET##b[p].x; hb.y = (_Float16)SET##b[p].y;   \
      hb.z = (_Float16)SET##b[p].z; hb.w = (_Float16)SET##b[p].w;   \
      *(half4*)&Ash[row][lc] = ha;                                  \
      *(half4*)&Bsh[row][lc] = hb;                                  \
    }                                                               \
  }

#define XCOMPUTE()                                                  \
  {                                                                 \
    half8 af[4], bf[4];                                             \
    _Pragma("unroll")                                               \
    for (int m = 0; m < 4; ++m)                                     \
      af[m] = *(const half8*)&Ash[wr * 64 + m * 16 + fr][fk * 8];   \
    _Pragma("unroll")                                               \
    for (int n = 0; n < 4; ++n)                                     \
      bf[n] = *(const half8*)&Bsh[wc * 64 + n * 16 + fr][fk * 8];   \
    _Pragma("unroll")                                               \
    for (int m = 0; m < 4; ++m)                                     \
      _Pragma("unroll")                                             \
      for (int n = 0; n < 4; ++n)                                   \
        acc[m][n] = __builtin_amdgcn_mfma_f32_16x16x32_f16(         \
            af[m], bf[n], acc[m][n], 0, 0, 0);                      \
  }

__global__ __launch_bounds__(256, 2) void xproj_mfma(
    const float* __restrict__ x, const float* __restrict__ Wxh,
    const float* __restrict__ bxh, float* __restrict__ xp) {
  __shared__ __align__(16) _Float16 Ash[128][40];
  __shared__ __align__(16) _Float16 Bsh[128][40];

  const int tid = threadIdx.x;
  const int m0 = blockIdx.x * 128;
  const int wv = tid >> 6;
  const int lane = tid & 63;
  const int wr = wv >> 1;
  const int wc = wv & 1;
  const int fr = lane & 15;
  const int fk = lane >> 4;

  const int lr = tid >> 3;
  const int lc = (tid & 7) * 4;

  f32x4 acc[4][4];
#pragma unroll
  for (int m = 0; m < 4; ++m)
#pragma unroll
    for (int n = 0; n < 4; ++n) {
      acc[m][n][0] = 0.f; acc[m][n][1] = 0.f;
      acc[m][n][2] = 0.f; acc[m][n][3] = 0.f;
    }

  float4 Aa[4], Ab[4], Ba[4], Bb[4];
  XLOADC(A, 0)

#pragma unroll 1
  for (int kc = 0; kc < RNN_IN; kc += 64) {
    XSTORE(A)
    { const int nk = kc + 32; XLOADC(B, nk < RNN_IN ? nk : RNN_IN - 32) }
    block_sync_lds();
    XCOMPUTE()
    block_sync_lds();
    XSTORE(B)
    { const int nk = kc + 64; XLOADC(A, nk < RNN_IN ? nk : RNN_IN - 32) }
    block_sync_lds();
    XCOMPUTE()
    block_sync_lds();
  }

  float bb[4];
#pragma unroll
  for (int n = 0; n < 4; ++n) bb[n] = bxh[wc * 64 + n * 16 + fr];
#pragma unroll
  for (int m = 0; m < 4; ++m) {
    const size_t rbase = (size_t)(m0 + wr * 64 + m * 16 + 4 * fk);
#pragma unroll
    for (int reg = 0; reg < 4; ++reg) {
      const size_t grow = rbase + reg;            // global row = b*2048 + t
      const size_t bidx = grow >> 11;             // batch
      const size_t tidx = grow & 2047;            // timestep
      float* rowp = &xp[(tidx * RNN_B + bidx) * RNN_H];
#pragma unroll
      for (int n = 0; n < 4; ++n)
        rowp[wc * 64 + n * 16 + fr] = acc[m][n][reg] + bb[n];
    }
  }
}

// fast tanh: 1 - 2/(exp(2x)+1) with raw v_rcp_f32; saturates at +-inf.
__device__ __forceinline__ float fast_tanh(float a) {
  const float e = __expf(2.f * a);
  return fmaf(-2.f, __builtin_amdgcn_rcpf(e + 1.f), 1.f);
}

// 4-lane (quad) sum via DPP quad_perm (pure VALU, ~4 cyc/op).
// 0xB1 = quad_perm [1,0,3,2] (xor 1); 0x4E = quad_perm [2,3,0,1] (xor 2).
__device__ __forceinline__ float quad_sum_dpp(float s) {
  int t = __builtin_amdgcn_mov_dpp(__builtin_bit_cast(int, s),
                                   0xB1, 0xF, 0xF, true);
  s += __builtin_bit_cast(float, t);
  t = __builtin_amdgcn_mov_dpp(__builtin_bit_cast(int, s),
                               0x4E, 0xF, 0xF, true);
  s += __builtin_bit_cast(float, t);
  return s;
}

// ---------------------------------------------------------------------------
// Phase 2: recurrence. grid=64 (one per batch), block=256 (4 waves, 1/SIMD).
// Thread (P = tid>>2, q = tid&3) owns rows 2P,2P+1, slice halves 32q..32q+31:
// W_hh[2P][32q..] and W_hh[2P+1][32q..] as 32 named half2 VGPRs.
// Per step: ONE 64-B h-slice read (4x ds_read_b128, 4 distinct addrs/wave =
// 2-way bank alias = free) feeds BOTH rows' dots; quad DPP reduce per row;
// one half2 (b32) write per row-pair (4-lane same-addr dup, conflict-free);
// 1 LDS-only barrier/step; float2 xp prefetch 4-deep.
// ---------------------------------------------------------------------------
union U8 { half8 v; float f[4]; };

#define WDECL(i) half2v w##i;
#define W_ALL(M) \
  M(0)  M(1)  M(2)  M(3)  M(4)  M(5)  M(6)  M(7)  \
  M(8)  M(9)  M(10) M(11) M(12) M(13) M(14) M(15) \
  M(16) M(17) M(18) M(19) M(20) M(21) M(22) M(23) \
  M(24) M(25) M(26) M(27) M(28) M(29) M(30) M(31)

// load one float4 from BASE[idx] -> two half2 regs
#define WLOAD2(BASE, i0, i1, idx)                             \
  {                                                           \
    const float4 f = BASE[idx];                               \
    half2v t; t.x = (_Float16)f.x; t.y = (_Float16)f.y;       \
    w##i0 = t;                                                \
    half2v s; s.x = (_Float16)f.z; s.y = (_Float16)f.w;       \
    w##i1 = s;                                                \
  }

// one 16-B h-chunk against 4 weight regs into 4 named acc chains
#define D4X(U, wa, wb, wc_, wd, x0, x1, x2, x3)                  \
  x0 = FDOT2(wa,  __builtin_bit_cast(half2v, (U).f[0]), x0);     \
  x1 = FDOT2(wb,  __builtin_bit_cast(half2v, (U).f[1]), x1);     \
  x2 = FDOT2(wc_, __builtin_bit_cast(half2v, (U).f[2]), x2);     \
  x3 = FDOT2(wd,  __builtin_bit_cast(half2v, (U).f[3]), x3);

#define SSTEP(CUR, NXT, PX, TNEXT)                                    \
  {                                                                   \
    const half8* hp = (const half8*)&hs[CUR][32 * q];                 \
    U8 u0, u1, u2, u3;                                                \
    u0.v = hp[0]; u1.v = hp[1]; u2.v = hp[2]; u3.v = hp[3];           \
    const float xinA = PX.x, xinB = PX.y;                             \
    PX = *(const float2*)(xpb + (size_t)(TNEXT) * (RNN_B * RNN_H));   \
    float a0 = 0.f, a1 = 0.f, a2 = 0.f, a3 = 0.f;                     \
    float b0 = 0.f, b1 = 0.f, b2 = 0.f, b3 = 0.f;                     \
    D4X(u0, w0,  w1,  w2,  w3,  a0, a1, a2, a3)                       \
    D4X(u1, w4,  w5,  w6,  w7,  a0, a1, a2, a3)                       \
    D4X(u2, w8,  w9,  w10, w11, a0, a1, a2, a3)                       \
    D4X(u3, w12, w13, w14, w15, a0, a1, a2, a3)                       \
    D4X(u0, w16, w17, w18, w19, b0, b1, b2, b3)                       \
    D4X(u1, w20, w21, w22, w23, b0, b1, b2, b3)                       \
    D4X(u2, w24, w25, w26, w27, b0, b1, b2, b3)                       \
    D4X(u3, w28, w29, w30, w31, b0, b1, b2, b3)                       \
    float sA = (a0 + a1) + (a2 + a3);                                 \
    float sB = (b0 + b1) + (b2 + b3);                                 \
    sA = quad_sum_dpp(sA);                                            \
    sB = quad_sum_dpp(sB);                                            \
    const float hvA = fast_tanh(biasA + xinA + sA);                   \
    const float hvB = fast_tanh(biasB + xinB + sB);                   \
    half2v pk; pk.x = (_Float16)hvA; pk.y = (_Float16)hvB;            \
    *(half2v*)&hs[NXT][2 * P] = pk;  /* 4 lanes, same addr+data */    \
    hvFA = hvA; hvFB = hvB;                                           \
    block_sync_lds();                                                 \
  }

__global__ __launch_bounds__(256, 1) void rnn_scan(
    const float* __restrict__ xq, const float* __restrict__ Whh,
    const float* __restrict__ bhh, const float* __restrict__ bh,
    const float* __restrict__ Wfc, const float* __restrict__ bfc,
    float* __restrict__ out) {
  const int b = blockIdx.x;
  const int tid = threadIdx.x;     // 0..255
  const int P = tid >> 2;          // row-pair 0..63 (rows 2P, 2P+1)
  const int q = tid & 3;           // 32-half slice (DPP quad = same P)

  __shared__ __align__(16) _Float16 hs[2][RNN_H];  // 2 x 256 B
  __shared__ float hfin[RNN_H];                    // final h (fp32) for FC

  const float4* wrowA4 =
      (const float4*)&Whh[(size_t)(2 * P) * RNN_H + 32 * q];
  const float4* wrowB4 =
      (const float4*)&Whh[(size_t)(2 * P + 1) * RNN_H + 32 * q];
  W_ALL(WDECL)
  WLOAD2(wrowA4, 0, 1, 0)   WLOAD2(wrowA4, 2, 3, 1)
  WLOAD2(wrowA4, 4, 5, 2)   WLOAD2(wrowA4, 6, 7, 3)
  WLOAD2(wrowA4, 8, 9, 4)   WLOAD2(wrowA4, 10, 11, 5)
  WLOAD2(wrowA4, 12, 13, 6) WLOAD2(wrowA4, 14, 15, 7)
  WLOAD2(wrowB4, 16, 17, 0) WLOAD2(wrowB4, 18, 19, 1)
  WLOAD2(wrowB4, 20, 21, 2) WLOAD2(wrowB4, 22, 23, 3)
  WLOAD2(wrowB4, 24, 25, 4) WLOAD2(wrowB4, 26, 27, 5)
  WLOAD2(wrowB4, 28, 29, 6) WLOAD2(wrowB4, 30, 31, 7)

  const float biasA = bhh[2 * P] + bh[2 * P];
  const float biasB = bhh[2 * P + 1] + bh[2 * P + 1];

  // zero h buffer 0 (256 B)
  if (tid < 64) ((float*)hs[0])[tid] = 0.f;
  block_sync_lds();

  // xp layout [t][b][h]: rows 2P,2P+1 of batch b -> one float2 per step
  const float* xpb = xq + (size_t)b * RNN_H + 2 * P;

  // 4-deep float2 prefetch (quad lanes duplicate the address -- coalesced)
  float2 p0 = *(const float2*)(xpb + (size_t)0 * (RNN_B * RNN_H));
  float2 p1 = *(const float2*)(xpb + (size_t)1 * (RNN_B * RNN_H));
  float2 p2 = *(const float2*)(xpb + (size_t)2 * (RNN_B * RNN_H));
  float2 p3 = *(const float2*)(xpb + (size_t)3 * (RNN_B * RNN_H));

  float hvFA = 0.f, hvFB = 0.f;

#pragma unroll 1
  for (int t = 0; t < RNN_S; t += 4) {
    const int n0 = (t + 4 < RNN_S) ? t + 4 : RNN_S - 1;
    const int n1 = (t + 5 < RNN_S) ? t + 5 : RNN_S - 1;
    const int n2 = (t + 6 < RNN_S) ? t + 6 : RNN_S - 1;
    const int n3 = (t + 7 < RNN_S) ? t + 7 : RNN_S - 1;
    SSTEP(0, 1, p0, n0)
    SSTEP(1, 0, p1, n1)
    SSTEP(0, 1, p2, n2)
    SSTEP(1, 0, p3, n3)
  }

  // final h (fp32, un-quantized) for rows 2P,2P+1 (all quad lanes identical)
  {
    float2 hf; hf.x = hvFA; hf.y = hvFB;
    *(float2*)&hfin[2 * P] = hf;
  }
  block_sync_lds();

  // fused FC: 3 threads, one output each (runs once -- negligible)
  if (tid < RNN_OUT) {
    float s = bfc[tid];
#pragma unroll 8
    for (int k = 0; k < RNN_H; ++k)
      s = fmaf(Wfc[(size_t)tid * RNN_H + k], hfin[k], s);
    out[b * RNN_OUT + tid] = s;
  }
}

extern "C" void kernel_launch(void* const* d_in, const int* in_sizes, int n_in,
                              void* d_out, int out_size, void* d_ws, size_t ws_size,
                              hipStream_t stream) {
  const float* x   = (const float*)d_in[0];
  const float* Wxh = (const float*)d_in[1];
  const float* bxh = (const float*)d_in[2];
  const float* Whh = (const float*)d_in[3];
  const float* bhh = (const float*)d_in[4];
  const float* bh  = (const float*)d_in[5];
  const float* Wfc = (const float*)d_in[6];
  const float* bfc = (const float*)d_in[7];
  float* out = (float*)d_out;
  float* xp  = (float*)d_ws;  // 2048*64*128*4 = 64 MiB, layout [t][b][h]

  xproj_mfma<<<dim3((RNN_B * RNN_S) / 128), dim3(256), 0, stream>>>(x, Wxh, bxh, xp);
  rnn_scan<<<dim3(RNN_B), dim3(256), 0, stream>>>(xp, Whh, bhh, bh, Wfc, bfc, out);
}